// Round 5
// baseline (10945.214 us; speedup 1.0000x reference)
//
#include <hip/hip_runtime.h>
#include <hip/hip_bf16.h>

typedef __hip_bfloat16 bf16;

__device__ __forceinline__ float b2f(bf16 v) { return __bfloat162float(v); }
__device__ __forceinline__ bf16 f2b(float v) { return __float2bfloat16(v); }
__device__ __forceinline__ float lo_bf(unsigned int u) {
  union { unsigned int i; float f; } v; v.i = u << 16; return v.f;
}
__device__ __forceinline__ float hi_bf(unsigned int u) {
  union { unsigned int i; float f; } v; v.i = u & 0xffff0000u; return v.f;
}
__device__ __forceinline__ float ldany(const float* p) { return *p; }
__device__ __forceinline__ float ldany(const bf16* p) { return b2f(*p); }
__device__ __forceinline__ void stany(float* p, float v) { *p = v; }
__device__ __forceinline__ void stany(bf16* p, float v) { *p = f2b(v); }

// ---------------- global average pool: x (C,HW) -> gap[C] ----------------
__global__ __launch_bounds__(256) void gap_kernel(const float* __restrict__ x,
                                                  float* __restrict__ gap,
                                                  int HW, float inv) {
  int c = blockIdx.x;
  const float* p = x + (size_t)c * HW;
  float s = 0.f;
  for (int i = threadIdx.x; i < HW; i += 256) s += p[i];
  __shared__ float red[256];
  red[threadIdx.x] = s;
  __syncthreads();
  for (int w = 128; w > 0; w >>= 1) {
    if (threadIdx.x < w) red[threadIdx.x] += red[threadIdx.x + w];
    __syncthreads();
  }
  if (threadIdx.x == 0) gap[c] = red[0] * inv;
}

// -------- scale[o] = 1 + sigmoid( sum_i att_w[o,i] * gap[i] ) ------------
__global__ __launch_bounds__(256) void atten_kernel(const float* __restrict__ w,
                                                    const float* __restrict__ gap,
                                                    float* __restrict__ scale, int Ci) {
  int o = blockIdx.x * 256 + threadIdx.x;
  if (o >= Ci) return;
  const float* wr = w + (size_t)o * Ci;
  float s = 0.f;
  for (int i = 0; i < Ci; ++i) s += wr[i] * gap[i];
  scale[o] = 1.f + 1.f / (1.f + expf(-s));
}

// ---------------- generic 1x1 conv over concat(A, B) ---------------------
// out[o,p] = bias[o] + sum_ci W[o,ci] * in[ci,p]; A optionally per-channel
// scaled (scaleA), B scaled by scalar scaleB.
template <typename TA, typename TB, typename TO>
__global__ __launch_bounds__(256) void conv1x1_kernel(
    const TA* __restrict__ A, const TB* __restrict__ B,
    const float* __restrict__ W, const float* __restrict__ bias,
    const float* __restrict__ scaleA, float scaleB,
    int Ci1, int Ci2, int HW,
    TO* __restrict__ outDst) {
  int p = blockIdx.x * 256 + threadIdx.x;
  int o0 = blockIdx.y * 8;
  int Ci = Ci1 + Ci2;
  float acc[8];
#pragma unroll
  for (int j = 0; j < 8; ++j) acc[j] = bias ? bias[o0 + j] : 0.f;
  const float* wp = W + (size_t)o0 * Ci;
  for (int ci = 0; ci < Ci1; ++ci) {
    float xv = ldany(&A[(size_t)ci * HW + p]);
    if (scaleA) xv *= scaleA[ci];
#pragma unroll
    for (int j = 0; j < 8; ++j) acc[j] += xv * wp[(size_t)j * Ci + ci];
  }
  for (int ci = 0; ci < Ci2; ++ci) {
    float xv = ldany(&B[(size_t)ci * HW + p]) * scaleB;
#pragma unroll
    for (int j = 0; j < 8; ++j) acc[j] += xv * wp[(size_t)j * Ci + Ci1 + ci];
  }
#pragma unroll
  for (int j = 0; j < 8; ++j) {
    stany(&outDst[(size_t)(o0 + j) * HW + p], acc[j]);
  }
}

// ------- bilinear 2x upsample, half-pixel centers, edge clamp ------------
template <typename TS>
__global__ __launch_bounds__(256) void upsample2x_kernel(const TS* __restrict__ src,
                                                         bf16* __restrict__ dst,
                                                         int C, int Hs, int Ws) {
  int H = Hs * 2, W = Ws * 2;
  int idx = blockIdx.x * 256 + threadIdx.x;
  int total = C * H * W;
  if (idx >= total) return;
  int x = idx % W;
  int y = (idx / W) % H;
  int c = idx / (W * H);
  float fy = y * 0.5f - 0.25f;
  float fx = x * 0.5f - 0.25f;
  int y0 = (int)floorf(fy), x0 = (int)floorf(fx);
  float wy1 = fy - (float)y0, wx1 = fx - (float)x0;
  int y0c = min(max(y0, 0), Hs - 1);
  int y1c = min(max(y0 + 1, 0), Hs - 1);
  int x0c = min(max(x0, 0), Ws - 1);
  int x1c = min(max(x0 + 1, 0), Ws - 1);
  const TS* s = src + (size_t)c * Hs * Ws;
  float v00 = ldany(&s[y0c * Ws + x0c]);
  float v01 = ldany(&s[y0c * Ws + x1c]);
  float v10 = ldany(&s[y1c * Ws + x0c]);
  float v11 = ldany(&s[y1c * Ws + x1c]);
  float v = (1.f - wy1) * ((1.f - wx1) * v00 + wx1 * v01)
          + wy1 * ((1.f - wx1) * v10 + wx1 * v11);
  dst[idx] = f2b(v);
}

// ------------- 3x3 conv pad=1; 8 outputs x 4 pixels per thread ----------
// in: bf16 (ws), W/bias: fp32 (harness inputs)
template <typename TO>
__global__ __launch_bounds__(256) void conv3x3_kernel(
    const bf16* __restrict__ in, const float* __restrict__ W,
    const float* __restrict__ bias,
    int Ci, int H, int Wd,
    TO* __restrict__ outDst) {
  int HW = H * Wd;
  int q = HW >> 2;
  int t = blockIdx.x * 256 + threadIdx.x;  // 0..q-1
  int o0 = blockIdx.y * 8;
  int pix[4], py_[4], pxx[4];
  float acc[4][8];
#pragma unroll
  for (int u = 0; u < 4; ++u) {
    pix[u] = t + u * q;
    py_[u] = pix[u] / Wd;
    pxx[u] = pix[u] - py_[u] * Wd;
#pragma unroll
    for (int j = 0; j < 8; ++j) acc[u][j] = 0.f;
  }
  for (int ci = 0; ci < Ci; ++ci) {
    float wr[8][9];
    const float* wb = W + ((size_t)o0 * Ci + ci) * 9;
#pragma unroll
    for (int j = 0; j < 8; ++j)
#pragma unroll
      for (int k = 0; k < 9; ++k) wr[j][k] = wb[(size_t)j * Ci * 9 + k];
    const bf16* ib = in + (size_t)ci * HW;
#pragma unroll
    for (int ty = 0; ty < 3; ++ty) {
#pragma unroll
      for (int tx = 0; tx < 3; ++tx) {
        int k = ty * 3 + tx;
#pragma unroll
        for (int u = 0; u < 4; ++u) {
          int yy = py_[u] + ty - 1;
          int xx = pxx[u] + tx - 1;
          float xv = ((unsigned)yy < (unsigned)H && (unsigned)xx < (unsigned)Wd)
                         ? b2f(ib[yy * Wd + xx]) : 0.f;
#pragma unroll
          for (int j = 0; j < 8; ++j) acc[u][j] += xv * wr[j][k];
        }
      }
    }
  }
#pragma unroll
  for (int j = 0; j < 8; ++j) {
    float bv = bias ? bias[o0 + j] : 0.f;
#pragma unroll
    for (int u = 0; u < 4; ++u) {
      stany(&outDst[(size_t)(o0 + j) * HW + pix[u]], acc[u][j] + bv);
    }
  }
}

// ------------- transpose dcn weight (256,2304) -> (2304,256) fp32 --------
__global__ __launch_bounds__(256) void wtrans_kernel(const float* __restrict__ w,
                                                     float* __restrict__ wT,
                                                     int Co, int CK) {
  int idx = blockIdx.x * 256 + threadIdx.x;
  if (idx >= Co * CK) return;
  int o = idx % Co;
  int ck = idx / Co;
  wT[idx] = w[(size_t)o * CK + ck];
}

// ---- modulated deformable conv v2, G=8, K=9, C=256, pad=1, + relu + ARM ----
// Phase A: sample 8-pixel tile -> LDS sval[px][c*9+k] (bf16, mask applied)
// Phase B: out[o,px] = relu( sum_ck wT[ck][o]*sval[px][ck] + b[o] ) + ARM[o,px]
__global__ __launch_bounds__(256) void mdcn_kernel(
    const bf16* __restrict__ UP, const bf16* __restrict__ OM,
    const float* __restrict__ wT, const float* __restrict__ dcn_b,
    const bf16* __restrict__ ARM, bf16* __restrict__ F,
    int H, int Wd) {
  int HW = H * Wd;
  __shared__ __align__(16) bf16 sval[8 * 2304];
  int p_base = blockIdx.x * 8;
  int lane_cg = threadIdx.x & 31;
  int grp = threadIdx.x >> 5;  // 0..7: half-wave handles pixel pxi=grp
  for (int it = 0; it < 72; ++it) {
    int gk = it;                       // 0..71
    int pxi = grp;
    int g = gk / 9, k = gk - g * 9;
    int ky = k / 3, kx = k - ky * 3;
    int p = p_base + pxi;
    int y = p / Wd, x = p - y * Wd;
    float dy = b2f(OM[(size_t)(g * 18 + k) * HW + p]);
    float dx = b2f(OM[(size_t)(g * 18 + 9 + k) * HW + p]);
    float mm = 1.f / (1.f + expf(-b2f(OM[(size_t)(144 + g * 9 + k) * HW + p])));
    float fpy = (float)(y - 1 + ky) + dy;
    float fpx = (float)(x - 1 + kx) + dx;
    fpy = fminf(fmaxf(fpy, -1.0e4f), 1.0e4f);
    fpx = fminf(fmaxf(fpx, -1.0e4f), 1.0e4f);
    float fy0 = floorf(fpy), fx0 = floorf(fpx);
    float wy1 = fpy - fy0, wx1 = fpx - fx0;
    int iy0 = (int)fy0, ix0 = (int)fx0;
    int c = g * 32 + lane_cg;
    const bf16* up = UP + (size_t)c * HW;
    bool vy0 = ((unsigned)iy0 < (unsigned)H);
    bool vy1 = ((unsigned)(iy0 + 1) < (unsigned)H);
    bool vx0 = ((unsigned)ix0 < (unsigned)Wd);
    bool vx1 = ((unsigned)(ix0 + 1) < (unsigned)Wd);
    int base = iy0 * Wd + ix0;
    float v00 = (vy0 && vx0) ? b2f(up[base]) : 0.f;
    float v01 = (vy0 && vx1) ? b2f(up[base + 1]) : 0.f;
    float v10 = (vy1 && vx0) ? b2f(up[base + Wd]) : 0.f;
    float v11 = (vy1 && vx1) ? b2f(up[base + Wd + 1]) : 0.f;
    float sv = mm * ((1.f - wy1) * ((1.f - wx1) * v00 + wx1 * v01)
                   + wy1 * ((1.f - wx1) * v10 + wx1 * v11));
    sval[pxi * 2304 + c * 9 + k] = f2b(sv);
  }
  __syncthreads();
  int o = threadIdx.x;  // 0..255 output channels
  float acc[8];
#pragma unroll
  for (int u = 0; u < 8; ++u) acc[u] = 0.f;
  for (int ck = 0; ck < 2304; ck += 8) {
    float w[8];
#pragma unroll
    for (int j = 0; j < 8; ++j) w[j] = wT[(size_t)(ck + j) * 256 + o];
#pragma unroll
    for (int u = 0; u < 8; ++u) {
      const uint4 raw = *reinterpret_cast<const uint4*>(&sval[u * 2304 + ck]);
      float a = acc[u];
      a = fmaf(lo_bf(raw.x), w[0], a);
      a = fmaf(hi_bf(raw.x), w[1], a);
      a = fmaf(lo_bf(raw.y), w[2], a);
      a = fmaf(hi_bf(raw.y), w[3], a);
      a = fmaf(lo_bf(raw.z), w[4], a);
      a = fmaf(hi_bf(raw.z), w[5], a);
      a = fmaf(lo_bf(raw.w), w[6], a);
      a = fmaf(hi_bf(raw.w), w[7], a);
      acc[u] = a;
    }
  }
  float bv = dcn_b[o];
#pragma unroll
  for (int u = 0; u < 8; ++u) {
    int p = p_base + u;
    float r = fmaxf(acc[u] + bv, 0.f);
    r += b2f(ARM[(size_t)o * HW + p]);
    F[(size_t)o * HW + p] = f2b(r);
  }
}

extern "C" void kernel_launch(void* const* d_in, const int* in_sizes, int n_in,
                              void* d_out, int out_size, void* d_ws, size_t ws_size,
                              hipStream_t stream) {
  // Inputs float32 (proven: round-3 bf16-decode sniffer fired).
  // Outputs float32 (round-4 evidence: bf16-written p2 decoded as fp32 gives
  // the observed 11.22 = max pixel-pair mismatch; bf16-correct would be ~0.05).
  const float* c2 = (const float*)d_in[0];
  const float* c3 = (const float*)d_in[1];
  const float* c4 = (const float*)d_in[2];
  const float* c5 = (const float*)d_in[3];
  const float* lat_w = (const float*)d_in[31];
  const float* lat_b = (const float*)d_in[32];
  float* out = (float*)d_out;
  (void)ws_size; (void)in_sizes; (void)n_in; (void)out_size;

  const size_t p2_off = 0;
  const size_t p3_off = 4194304;
  const size_t p4_off = p3_off + 1048576;
  const size_t p5_off = p4_off + 262144;

  // ---- workspace layout (ws_size >= 28MB proven by round-3 probe) ----
  // UP(8MB bf16) | ARM(8MB) | FB(8MB, off_feat & F alias) | WT(2.25MB fp32)
  char* ws = (char*)d_ws;
  bf16* UP  = (bf16*)(ws);
  bf16* ARM = (bf16*)(ws + 8388608);
  bf16* FB  = (bf16*)(ws + 16777216);
  float* WT = (float*)(ws + 25165824);
  float* GAP = (float*)(ws + 27525120);
  float* SC  = (float*)(ws + 27533312);
  // OM (216ch bf16, max 6.75MB) borrows the p2 output region (16.8MB fp32);
  // p2 itself is written only by the final conv, after mdcn consumed OM.
  bf16* OM = (bf16*)(out + p2_off);

  // ---- p5 = conv1x1(c5, lat_w, lat_b), 16x16, fp32 out ----
  conv1x1_kernel<float, float, float><<<dim3(1, 32), 256, 0, stream>>>(
      c5, (const float*)nullptr, lat_w, lat_b, nullptr, 0.f, 2048, 0, 256,
      out + p5_off);

  struct Lv {
    const float* featl; int Ci; int H; int W;
    float* pdst; int wbase;
  };
  Lv levels[3] = {
      {c4, 1024, 32, 32, out + p4_off, 4},
      {c3, 512, 64, 64, out + p3_off, 13},
      {c2, 256, 128, 128, out + p2_off, 22},
  };

  for (int li = 0; li < 3; ++li) {
    const Lv& L = levels[li];
    const float* att_w = (const float*)d_in[L.wbase + 0];
    const float* fsm_w = (const float*)d_in[L.wbase + 1];
    const float* off_w = (const float*)d_in[L.wbase + 2];
    const float* om_w  = (const float*)d_in[L.wbase + 3];
    const float* om_b  = (const float*)d_in[L.wbase + 4];
    const float* dcn_w = (const float*)d_in[L.wbase + 5];
    const float* dcn_b = (const float*)d_in[L.wbase + 6];
    const float* out_w = (const float*)d_in[L.wbase + 7];
    const float* out_b = (const float*)d_in[L.wbase + 8];
    int HW = L.H * L.W;

    // 1) feat_up = bilinear 2x of previous level's F (fp32 p5 for level 0,
    //    bf16 FB otherwise; FB still holds prev F at this point)
    if (li == 0) {
      upsample2x_kernel<float><<<(256 * HW) / 256, 256, 0, stream>>>(
          out + p5_off, UP, 256, L.H / 2, L.W / 2);
    } else {
      upsample2x_kernel<bf16><<<(256 * HW) / 256, 256, 0, stream>>>(
          FB, UP, 256, L.H / 2, L.W / 2);
    }
    // 2) FSM: gap -> atten -> scaled 1x1 proj -> ARM (bf16)
    gap_kernel<<<L.Ci, 256, 0, stream>>>(L.featl, GAP, HW, 1.f / (float)HW);
    atten_kernel<<<L.Ci / 256, 256, 0, stream>>>(att_w, GAP, SC, L.Ci);
    conv1x1_kernel<float, float, bf16><<<dim3(HW / 256, 32), 256, 0, stream>>>(
        L.featl, (const float*)nullptr, fsm_w, nullptr, SC, 0.f, L.Ci, 0, HW,
        ARM);
    // 3) off_feat = conv1x1(concat(ARM, 2*UP)) -> FB (bf16)
    conv1x1_kernel<bf16, bf16, bf16><<<dim3(HW / 256, 32), 256, 0, stream>>>(
        ARM, UP, off_w, nullptr, nullptr, 2.f, 256, 256, HW, FB);
    // 4) om = conv3x3(FB) + b, 216 ch -> OM (bf16, p2 region of d_out)
    conv3x3_kernel<bf16><<<dim3(HW / 1024, 27), 256, 0, stream>>>(
        FB, om_w, om_b, 256, L.H, L.W, OM);
    // 5) dcn weight transpose (fp32)
    wtrans_kernel<<<2304, 256, 0, stream>>>(dcn_w, WT, 256, 2304);
    // 6) F = relu(mdcn(UP, OM)) + ARM -> FB (bf16; off_feat dead now)
    mdcn_kernel<<<HW / 8, 256, 0, stream>>>(UP, OM, WT, dcn_b, ARM, FB, L.H, L.W);
    // 7) p = conv3x3(F, out_w) + out_b (fp32 out)
    conv3x3_kernel<float><<<dim3(HW / 1024, 32), 256, 0, stream>>>(
        FB, out_w, out_b, 256, L.H, L.W, L.pdst);
  }
}

// Round 7
// 3719.331 us; speedup vs baseline: 2.9428x; 2.9428x over previous
//
#include <hip/hip_runtime.h>
#include <hip/hip_bf16.h>

typedef __hip_bfloat16 bf16;
typedef __attribute__((ext_vector_type(8))) short bf16x8;
typedef __attribute__((ext_vector_type(4))) float floatx4;

__device__ __forceinline__ float b2f(bf16 v) { return __bfloat162float(v); }
__device__ __forceinline__ bf16 f2b(float v) { return __float2bfloat16(v); }
__device__ __forceinline__ float lo_bf(unsigned int u) {
  union { unsigned int i; float f; } v; v.i = u << 16; return v.f;
}
__device__ __forceinline__ float hi_bf(unsigned int u) {
  union { unsigned int i; float f; } v; v.i = u & 0xffff0000u; return v.f;
}
__device__ __forceinline__ float ldany(const float* p) { return *p; }
__device__ __forceinline__ float ldany(const bf16* p) { return b2f(*p); }
__device__ __forceinline__ void stany(float* p, float v) { *p = v; }
__device__ __forceinline__ void stany(bf16* p, float v) { *p = f2b(v); }

// ---------------- global average pool: x (C,HW) -> gap[C] ----------------
__global__ __launch_bounds__(256) void gap_kernel(const float* __restrict__ x,
                                                  float* __restrict__ gap,
                                                  int HW, float inv) {
  int c = blockIdx.x;
  const float* p = x + (size_t)c * HW;
  float s = 0.f;
  for (int i = threadIdx.x; i < HW; i += 256) s += p[i];
  __shared__ float red[256];
  red[threadIdx.x] = s;
  __syncthreads();
  for (int w = 128; w > 0; w >>= 1) {
    if (threadIdx.x < w) red[threadIdx.x] += red[threadIdx.x + w];
    __syncthreads();
  }
  if (threadIdx.x == 0) gap[c] = red[0] * inv;
}

// -------- scale[o] = 1 + sigmoid( sum_i att_w[o,i] * gap[i] ) ------------
__global__ __launch_bounds__(256) void atten_kernel(const float* __restrict__ w,
                                                    const float* __restrict__ gap,
                                                    float* __restrict__ scale, int Ci) {
  int o = blockIdx.x * 256 + threadIdx.x;
  if (o >= Ci) return;
  const float* wr = w + (size_t)o * Ci;
  float s = 0.f;
  for (int i = 0; i < Ci; ++i) s += wr[i] * gap[i];
  scale[o] = 1.f + 1.f / (1.f + expf(-s));
}

// ---------------- generic 1x1 conv over concat(A, B) ---------------------
template <typename TA, typename TB, typename TO>
__global__ __launch_bounds__(256) void conv1x1_kernel(
    const TA* __restrict__ A, const TB* __restrict__ B,
    const float* __restrict__ W, const float* __restrict__ bias,
    const float* __restrict__ scaleA, float scaleB,
    int Ci1, int Ci2, int HW,
    TO* __restrict__ outDst) {
  int p = blockIdx.x * 256 + threadIdx.x;
  int o0 = blockIdx.y * 8;
  int Ci = Ci1 + Ci2;
  float acc[8];
#pragma unroll
  for (int j = 0; j < 8; ++j) acc[j] = bias ? bias[o0 + j] : 0.f;
  const float* wp = W + (size_t)o0 * Ci;
  for (int ci = 0; ci < Ci1; ++ci) {
    float xv = ldany(&A[(size_t)ci * HW + p]);
    if (scaleA) xv *= scaleA[ci];
#pragma unroll
    for (int j = 0; j < 8; ++j) acc[j] += xv * wp[(size_t)j * Ci + ci];
  }
  for (int ci = 0; ci < Ci2; ++ci) {
    float xv = ldany(&B[(size_t)ci * HW + p]) * scaleB;
#pragma unroll
    for (int j = 0; j < 8; ++j) acc[j] += xv * wp[(size_t)j * Ci + Ci1 + ci];
  }
#pragma unroll
  for (int j = 0; j < 8; ++j) {
    stany(&outDst[(size_t)(o0 + j) * HW + p], acc[j]);
  }
}

// ------- bilinear 2x upsample, half-pixel centers, edge clamp ------------
template <typename TS>
__global__ __launch_bounds__(256) void upsample2x_kernel(const TS* __restrict__ src,
                                                         bf16* __restrict__ dst,
                                                         int C, int Hs, int Ws) {
  int H = Hs * 2, W = Ws * 2;
  int idx = blockIdx.x * 256 + threadIdx.x;
  int total = C * H * W;
  if (idx >= total) return;
  int x = idx % W;
  int y = (idx / W) % H;
  int c = idx / (W * H);
  float fy = y * 0.5f - 0.25f;
  float fx = x * 0.5f - 0.25f;
  int y0 = (int)floorf(fy), x0 = (int)floorf(fx);
  float wy1 = fy - (float)y0, wx1 = fx - (float)x0;
  int y0c = min(max(y0, 0), Hs - 1);
  int y1c = min(max(y0 + 1, 0), Hs - 1);
  int x0c = min(max(x0, 0), Ws - 1);
  int x1c = min(max(x0 + 1, 0), Ws - 1);
  const TS* s = src + (size_t)c * Hs * Ws;
  float v00 = ldany(&s[y0c * Ws + x0c]);
  float v01 = ldany(&s[y0c * Ws + x1c]);
  float v10 = ldany(&s[y1c * Ws + x0c]);
  float v11 = ldany(&s[y1c * Ws + x1c]);
  float v = (1.f - wy1) * ((1.f - wx1) * v00 + wx1 * v01)
          + wy1 * ((1.f - wx1) * v10 + wx1 * v11);
  dst[idx] = f2b(v);
}

// ------- pack 3x3 conv weights (fp32 OIHW) -> bf16 MFMA-B layout ---------
// BP[(((c*9+tap)*4+q)*256 + o)*8 + j] = w[o][c*32+q*8+j][tap], zero-pad o>=Co.
__global__ __launch_bounds__(256) void packw3_kernel(const float* __restrict__ w,
                                                     bf16* __restrict__ BP,
                                                     int Ci, int Co) {
  int idx = blockIdx.x * 256 + threadIdx.x;
  int total = Ci * 9 * 256;
  if (idx >= total) return;
  int j = idx & 7;
  int t1 = idx >> 3;
  int o = t1 & 255;
  int t2 = t1 >> 8;
  int q = t2 & 3;
  int t3 = t2 >> 2;
  int tap = t3 % 9;
  int c = t3 / 9;
  int ci = c * 32 + q * 8 + j;
  float v = (o < Co) ? w[((size_t)o * Ci + ci) * 9 + tap] : 0.f;
  BP[idx] = f2b(v);
}

// ------------- 3x3 conv pad=1, MFMA implicit GEMM ------------------------
// Block: 32-pixel row segment x 128 out-channels; 4 waves (2 pixgroup x
// 2 cogroup); per 32-ci chunk: phase A stages 9-tap im2col into LDS,
// phase B runs 16x16x32 bf16 MFMAs with B-frags from packed BP.
#define RS3 296  // 288 + 8 pad (16B-aligned rows)
template <typename TO>
__global__ __launch_bounds__(256) void conv3x3_mfma_kernel(
    const bf16* __restrict__ in, const bf16* __restrict__ BP,
    const float* __restrict__ bias,
    int Ci, int H, int W, int Co, TO* __restrict__ out) {
  __shared__ __align__(16) bf16 sA[32 * RS3];
  int HW = H * W;
  int segs = W >> 5;
  int y = blockIdx.x / segs;
  int x0 = (blockIdx.x - y * segs) << 5;
  int tid = threadIdx.x;
  int pix = tid & 31, sub = tid >> 5;
  int lane = tid & 63, wave = tid >> 6;
  int pixgroup = wave & 1, cogroup = wave >> 1;
  int q = lane >> 4, n = lane & 15;

  floatx4 acc[4];
#pragma unroll
  for (int nt = 0; nt < 4; ++nt) acc[nt] = (floatx4)0.f;

  int nchunks = Ci >> 5;
  for (int c = 0; c < nchunks; ++c) {
    // ---- phase A: im2col chunk -> LDS (coalesced in x) ----
    int ci0 = c << 5;
#pragma unroll
    for (int it = 0; it < 36; ++it) {
      int task = it * 8 + sub;          // 0..287 = tap*32 + cil
      int tap = task >> 5;
      int cil = task & 31;
      int dy = tap / 3 - 1, dx = tap % 3 - 1;
      int yy = y + dy, xx = x0 + pix + dx;
      bf16 v = ((unsigned)yy < (unsigned)H && (unsigned)xx < (unsigned)W)
                   ? in[(size_t)(ci0 + cil) * HW + yy * W + xx]
                   : f2b(0.f);
      sA[pix * RS3 + task] = v;
    }
    __syncthreads();
    // ---- phase B: 9 taps x (1 a-frag + 4 b-frags + 4 MFMA) ----
    const bf16* bpc = BP + ((size_t)(c * 9) * 4) * 256 * 8;
#pragma unroll
    for (int tap = 0; tap < 9; ++tap) {
      bf16x8 a = *reinterpret_cast<const bf16x8*>(
          &sA[(pixgroup * 16 + n) * RS3 + tap * 32 + q * 8]);
      // NOTE blockIdx.y*128: round-6 bug was omitting this term (channels
      // 128..255 got channels 0..127's weights).
      const bf16* bp =
          bpc + ((size_t)(tap * 4 + q) * 256 + blockIdx.y * 128 + cogroup * 64) * 8;
#pragma unroll
      for (int nt = 0; nt < 4; ++nt) {
        bf16x8 b = *reinterpret_cast<const bf16x8*>(&bp[(nt * 16 + n) * 8]);
        acc[nt] = __builtin_amdgcn_mfma_f32_16x16x32_bf16(a, b, acc[nt], 0, 0, 0);
      }
    }
    __syncthreads();
  }

  // ---- store: C/D layout col=lane&15 (=o), row=q*4+reg (=pixel) ----
  int pbase = y * W + x0 + pixgroup * 16 + q * 4;
#pragma unroll
  for (int nt = 0; nt < 4; ++nt) {
    int o = blockIdx.y * 128 + cogroup * 64 + nt * 16 + n;
    if (o < Co) {
      float bv = bias ? bias[o] : 0.f;
      TO* dst = out + (size_t)o * HW + pbase;
#pragma unroll
      for (int r = 0; r < 4; ++r) stany(&dst[r], acc[nt][r] + bv);
    }
  }
}

// ------------- transpose dcn weight (256,2304) -> (2304,256) fp32 --------
__global__ __launch_bounds__(256) void wtrans_kernel(const float* __restrict__ w,
                                                     float* __restrict__ wT,
                                                     int Co, int CK) {
  int idx = blockIdx.x * 256 + threadIdx.x;
  if (idx >= Co * CK) return;
  int o = idx % Co;
  int ck = idx / Co;
  wT[idx] = w[(size_t)o * CK + ck];
}

// ---- modulated deformable conv v2, G=8, K=9, C=256, pad=1, + relu + ARM ----
__global__ __launch_bounds__(256) void mdcn_kernel(
    const bf16* __restrict__ UP, const bf16* __restrict__ OM,
    const float* __restrict__ wT, const float* __restrict__ dcn_b,
    const bf16* __restrict__ ARM, bf16* __restrict__ F,
    int H, int Wd) {
  int HW = H * Wd;
  __shared__ __align__(16) bf16 sval[8 * 2304];
  int p_base = blockIdx.x * 8;
  int lane_cg = threadIdx.x & 31;
  int grp = threadIdx.x >> 5;  // 0..7: half-wave handles pixel pxi=grp
  for (int it = 0; it < 72; ++it) {
    int gk = it;                       // 0..71
    int pxi = grp;
    int g = gk / 9, k = gk - g * 9;
    int ky = k / 3, kx = k - ky * 3;
    int p = p_base + pxi;
    int y = p / Wd, x = p - y * Wd;
    float dy = b2f(OM[(size_t)(g * 18 + k) * HW + p]);
    float dx = b2f(OM[(size_t)(g * 18 + 9 + k) * HW + p]);
    float mm = 1.f / (1.f + expf(-b2f(OM[(size_t)(144 + g * 9 + k) * HW + p])));
    float fpy = (float)(y - 1 + ky) + dy;
    float fpx = (float)(x - 1 + kx) + dx;
    fpy = fminf(fmaxf(fpy, -1.0e4f), 1.0e4f);
    fpx = fminf(fmaxf(fpx, -1.0e4f), 1.0e4f);
    float fy0 = floorf(fpy), fx0 = floorf(fpx);
    float wy1 = fpy - fy0, wx1 = fpx - fx0;
    int iy0 = (int)fy0, ix0 = (int)fx0;
    int c = g * 32 + lane_cg;
    const bf16* up = UP + (size_t)c * HW;
    bool vy0 = ((unsigned)iy0 < (unsigned)H);
    bool vy1 = ((unsigned)(iy0 + 1) < (unsigned)H);
    bool vx0 = ((unsigned)ix0 < (unsigned)Wd);
    bool vx1 = ((unsigned)(ix0 + 1) < (unsigned)Wd);
    int base = iy0 * Wd + ix0;
    float v00 = (vy0 && vx0) ? b2f(up[base]) : 0.f;
    float v01 = (vy0 && vx1) ? b2f(up[base + 1]) : 0.f;
    float v10 = (vy1 && vx0) ? b2f(up[base + Wd]) : 0.f;
    float v11 = (vy1 && vx1) ? b2f(up[base + Wd + 1]) : 0.f;
    float sv = mm * ((1.f - wy1) * ((1.f - wx1) * v00 + wx1 * v01)
                   + wy1 * ((1.f - wx1) * v10 + wx1 * v11));
    sval[pxi * 2304 + c * 9 + k] = f2b(sv);
  }
  __syncthreads();
  int o = threadIdx.x;  // 0..255 output channels
  float acc[8];
#pragma unroll
  for (int u = 0; u < 8; ++u) acc[u] = 0.f;
  for (int ck = 0; ck < 2304; ck += 8) {
    float w[8];
#pragma unroll
    for (int j = 0; j < 8; ++j) w[j] = wT[(size_t)(ck + j) * 256 + o];
#pragma unroll
    for (int u = 0; u < 8; ++u) {
      const uint4 raw = *reinterpret_cast<const uint4*>(&sval[u * 2304 + ck]);
      float a = acc[u];
      a = fmaf(lo_bf(raw.x), w[0], a);
      a = fmaf(hi_bf(raw.x), w[1], a);
      a = fmaf(lo_bf(raw.y), w[2], a);
      a = fmaf(hi_bf(raw.y), w[3], a);
      a = fmaf(lo_bf(raw.z), w[4], a);
      a = fmaf(hi_bf(raw.z), w[5], a);
      a = fmaf(lo_bf(raw.w), w[6], a);
      a = fmaf(hi_bf(raw.w), w[7], a);
      acc[u] = a;
    }
  }
  float bv = dcn_b[o];
#pragma unroll
  for (int u = 0; u < 8; ++u) {
    int p = p_base + u;
    float r = fmaxf(acc[u] + bv, 0.f);
    r += b2f(ARM[(size_t)o * HW + p]);
    F[(size_t)o * HW + p] = f2b(r);
  }
}

extern "C" void kernel_launch(void* const* d_in, const int* in_sizes, int n_in,
                              void* d_out, int out_size, void* d_ws, size_t ws_size,
                              hipStream_t stream) {
  // Inputs float32, outputs float32 (established rounds 3-5).
  const float* c2 = (const float*)d_in[0];
  const float* c3 = (const float*)d_in[1];
  const float* c4 = (const float*)d_in[2];
  const float* c5 = (const float*)d_in[3];
  const float* lat_w = (const float*)d_in[31];
  const float* lat_b = (const float*)d_in[32];
  float* out = (float*)d_out;
  (void)ws_size; (void)in_sizes; (void)n_in; (void)out_size;

  const size_t p2_off = 0;
  const size_t p3_off = 4194304;
  const size_t p4_off = p3_off + 1048576;
  const size_t p5_off = p4_off + 262144;

  // ---- workspace layout (ws_size >= 28MB proven by round-3 probe) ----
  // UP(8MB bf16) | ARM(8MB) | FB(8MB) | WT(2.25MB fp32) | GAP | SC | BP(1.2MB)
  char* ws = (char*)d_ws;
  bf16* UP  = (bf16*)(ws);
  bf16* ARM = (bf16*)(ws + 8388608);
  bf16* FB  = (bf16*)(ws + 16777216);
  float* WT = (float*)(ws + 25165824);
  float* GAP = (float*)(ws + 27525120);
  float* SC  = (float*)(ws + 27533312);
  bf16* BP  = (bf16*)(ws + 27541504);   // 1.125MB, ends 27.4MB < 28MB
  // OM (216ch bf16, max 6.75MB) borrows the p2 output region (16.8MB fp32);
  // p2 itself is written only by the final conv, after mdcn consumed OM.
  bf16* OM = (bf16*)(out + p2_off);

  // ---- p5 = conv1x1(c5, lat_w, lat_b), 16x16, fp32 out ----
  conv1x1_kernel<float, float, float><<<dim3(1, 32), 256, 0, stream>>>(
      c5, (const float*)nullptr, lat_w, lat_b, nullptr, 0.f, 2048, 0, 256,
      out + p5_off);

  struct Lv {
    const float* featl; int Ci; int H; int W;
    float* pdst; int wbase;
  };
  Lv levels[3] = {
      {c4, 1024, 32, 32, out + p4_off, 4},
      {c3, 512, 64, 64, out + p3_off, 13},
      {c2, 256, 128, 128, out + p2_off, 22},
  };

  for (int li = 0; li < 3; ++li) {
    const Lv& L = levels[li];
    const float* att_w = (const float*)d_in[L.wbase + 0];
    const float* fsm_w = (const float*)d_in[L.wbase + 1];
    const float* off_w = (const float*)d_in[L.wbase + 2];
    const float* om_w  = (const float*)d_in[L.wbase + 3];
    const float* om_b  = (const float*)d_in[L.wbase + 4];
    const float* dcn_w = (const float*)d_in[L.wbase + 5];
    const float* dcn_b = (const float*)d_in[L.wbase + 6];
    const float* out_w = (const float*)d_in[L.wbase + 7];
    const float* out_b = (const float*)d_in[L.wbase + 8];
    int HW = L.H * L.W;

    // 1) feat_up = bilinear 2x of previous level's F
    if (li == 0) {
      upsample2x_kernel<float><<<(256 * HW) / 256, 256, 0, stream>>>(
          out + p5_off, UP, 256, L.H / 2, L.W / 2);
    } else {
      upsample2x_kernel<bf16><<<(256 * HW) / 256, 256, 0, stream>>>(
          FB, UP, 256, L.H / 2, L.W / 2);
    }
    // 2) FSM: gap -> atten -> scaled 1x1 proj -> ARM (bf16)
    gap_kernel<<<L.Ci, 256, 0, stream>>>(L.featl, GAP, HW, 1.f / (float)HW);
    atten_kernel<<<L.Ci / 256, 256, 0, stream>>>(att_w, GAP, SC, L.Ci);
    conv1x1_kernel<float, float, bf16><<<dim3(HW / 256, 32), 256, 0, stream>>>(
        L.featl, (const float*)nullptr, fsm_w, nullptr, SC, 0.f, L.Ci, 0, HW,
        ARM);
    // 3) off_feat = conv1x1(concat(ARM, 2*UP)) -> FB (bf16)
    conv1x1_kernel<bf16, bf16, bf16><<<dim3(HW / 256, 32), 256, 0, stream>>>(
        ARM, UP, off_w, nullptr, nullptr, 2.f, 256, 256, HW, FB);
    // 4) om = conv3x3(FB) + b, 216 ch -> OM (bf16, p2 region of d_out)
    packw3_kernel<<<2304, 256, 0, stream>>>(om_w, BP, 256, 216);
    conv3x3_mfma_kernel<bf16><<<dim3(HW / 32, 2), 256, 0, stream>>>(
        FB, BP, om_b, 256, L.H, L.W, 216, OM);
    // 5) dcn weight transpose (fp32)
    wtrans_kernel<<<2304, 256, 0, stream>>>(dcn_w, WT, 256, 2304);
    // 6) F = relu(mdcn(UP, OM)) + ARM -> FB (bf16; off_feat dead now)
    mdcn_kernel<<<HW / 8, 256, 0, stream>>>(UP, OM, WT, dcn_b, ARM, FB, L.H, L.W);
    // 7) p = conv3x3(F, out_w) + out_b (fp32 out, MFMA)
    packw3_kernel<<<2304, 256, 0, stream>>>(out_w, BP, 256, 256);
    conv3x3_mfma_kernel<float><<<dim3(HW / 32, 2), 256, 0, stream>>>(
        FB, BP, out_b, 256, L.H, L.W, 256, L.pdst);
  }
}

// Round 8
// 1381.963 us; speedup vs baseline: 7.9200x; 2.6913x over previous
//
#include <hip/hip_runtime.h>
#include <hip/hip_bf16.h>

typedef __hip_bfloat16 bf16;
typedef __attribute__((ext_vector_type(8))) short bf16x8;
typedef __attribute__((ext_vector_type(4))) float floatx4;

__device__ __forceinline__ float b2f(bf16 v) { return __bfloat162float(v); }
__device__ __forceinline__ bf16 f2b(float v) { return __float2bfloat16(v); }
__device__ __forceinline__ float us2f(unsigned short u) {
  union { unsigned int i; float f; } v; v.i = ((unsigned int)u) << 16; return v.f;
}
__device__ __forceinline__ unsigned short f2us(float f) {
  bf16 h = f2b(f); return *(unsigned short*)&h;
}

// ---------------- global average pool: x (C,HW) fp32 NCHW -> gap[C] ------
__global__ __launch_bounds__(256) void gap_kernel(const float* __restrict__ x,
                                                  float* __restrict__ gap,
                                                  int HW, float inv) {
  int c = blockIdx.x;
  const float* p = x + (size_t)c * HW;
  float s = 0.f;
  for (int i = threadIdx.x; i < HW; i += 256) s += p[i];
  __shared__ float red[256];
  red[threadIdx.x] = s;
  __syncthreads();
  for (int w = 128; w > 0; w >>= 1) {
    if (threadIdx.x < w) red[threadIdx.x] += red[threadIdx.x + w];
    __syncthreads();
  }
  if (threadIdx.x == 0) gap[c] = red[0] * inv;
}

// -------- scale[o] = 1 + sigmoid( sum_i att_w[o,i] * gap[i] ) ------------
__global__ __launch_bounds__(256) void atten_kernel(const float* __restrict__ w,
                                                    const float* __restrict__ gap,
                                                    float* __restrict__ scale, int Ci) {
  int o = blockIdx.x * 256 + threadIdx.x;
  if (o >= Ci) return;
  const float* wr = w + (size_t)o * Ci;
  float s = 0.f;
  for (int i = 0; i < Ci; ++i) s += wr[i] * gap[i];
  scale[o] = 1.f + 1.f / (1.f + expf(-s));
}

// ---- bilinear 2x upsample NHWC(256) -> NHWC(256), half-pixel, clamp -----
__global__ __launch_bounds__(256) void upsample2x_nhwc_kernel(
    const bf16* __restrict__ src, bf16* __restrict__ dst, int Hs, int Ws) {
  int p = blockIdx.x;       // output pixel
  int c = threadIdx.x;      // channel
  int W = Ws * 2;
  int y = p / W, x = p - y * W;
  float fy = y * 0.5f - 0.25f;
  float fx = x * 0.5f - 0.25f;
  int y0 = (int)floorf(fy), x0 = (int)floorf(fx);
  float wy1 = fy - (float)y0, wx1 = fx - (float)x0;
  int y0c = min(max(y0, 0), Hs - 1);
  int y1c = min(max(y0 + 1, 0), Hs - 1);
  int x0c = min(max(x0, 0), Ws - 1);
  int x1c = min(max(x0 + 1, 0), Ws - 1);
  float v00 = b2f(src[(size_t)(y0c * Ws + x0c) * 256 + c]);
  float v01 = b2f(src[(size_t)(y0c * Ws + x1c) * 256 + c]);
  float v10 = b2f(src[(size_t)(y1c * Ws + x0c) * 256 + c]);
  float v11 = b2f(src[(size_t)(y1c * Ws + x1c) * 256 + c]);
  float v = (1.f - wy1) * ((1.f - wx1) * v00 + wx1 * v01)
          + wy1 * ((1.f - wx1) * v10 + wx1 * v11);
  dst[(size_t)p * 256 + c] = f2b(v);
}

// ------- pack GEMM weights (fp32 [256][K]) -> bf16 MFMA-B layout ---------
// BP[((k>>3)*256 + o)*8 + (k&7)] = w[o*K + k].  grid = K blocks.
__global__ __launch_bounds__(256) void packw1_kernel(const float* __restrict__ w,
                                                     bf16* __restrict__ BP, int K) {
  int idx = blockIdx.x * 256 + threadIdx.x;
  int j = idx & 7;
  int o = (idx >> 3) & 255;
  int kc8 = idx >> 11;
  int k = kc8 * 8 + j;
  BP[idx] = f2b(w[(size_t)o * K + k]);
}

// ------- pack 3x3 conv weights (fp32 OIHW, Ci=256) -> bf16 B layout ------
// BP[(((c*9+tap)*4+q)*256 + o)*8 + j] = w[o][c*32+q*8+j][tap]; zero o>=Co.
__global__ __launch_bounds__(256) void packw3_kernel(const float* __restrict__ w,
                                                     bf16* __restrict__ BP,
                                                     int Ci, int Co) {
  int idx = blockIdx.x * 256 + threadIdx.x;
  int total = Ci * 9 * 256;
  if (idx >= total) return;
  int j = idx & 7;
  int t1 = idx >> 3;
  int o = t1 & 255;
  int t2 = t1 >> 8;
  int q = t2 & 3;
  int t3 = t2 >> 2;
  int tap = t3 % 9;
  int c = t3 / 9;
  int ci = c * 32 + q * 8 + j;
  float v = (o < Co) ? w[((size_t)o * Ci + ci) * 9 + tap] : 0.f;
  BP[idx] = f2b(v);
}

// ------------- 1x1 conv as MFMA GEMM -------------------------------------
// Block: 32 px x 128 o (grid (HW/32, 2)), 4 waves = 2 pixgroup x 2 cogroup.
// A1: NCHW fp32 (w/ optional per-channel scaleA) or NHWC bf16 (stride 256).
// A2 (optional): NHWC bf16 stride 256, scaled by scaleB. K = Ci1+Ci2.
// out1: fp32 NCHW (optional), out2: bf16 NHWC stride ns2 (optional).
template <bool NCHW1, typename TA1>
__global__ __launch_bounds__(256) void conv1x1_mfma_kernel(
    const TA1* __restrict__ A1, const float* __restrict__ scaleA,
    const bf16* __restrict__ A2, float scaleB,
    int Ci1, int Ci2, int HW,
    const bf16* __restrict__ BP, const float* __restrict__ bias,
    float* __restrict__ out1, bf16* __restrict__ out2, int ns2) {
  __shared__ __align__(16) bf16 sA[1024];   // [4 q][32 px][8]
  int p0 = blockIdx.x * 32;
  int tid = threadIdx.x;
  int pix = tid & 31, sub = tid >> 5;       // fp32-NCHW staging mapping
  int pix2 = tid >> 3, sub8 = tid & 7;      // NHWC staging mapping
  int lane = tid & 63, wave = tid >> 6;
  int pg = wave & 1, cg = wave >> 1;
  int q = lane >> 4, n = lane & 15;

  floatx4 acc[4];
#pragma unroll
  for (int nt = 0; nt < 4; ++nt) acc[nt] = (floatx4)0.f;

  int nch = (Ci1 + Ci2) >> 5;
  for (int kc = 0; kc < nch; ++kc) {
    int ci0 = kc << 5;
    if (NCHW1 && ci0 < Ci1) {
#pragma unroll
      for (int it = 0; it < 4; ++it) {
        int cil = it * 8 + sub;
        float x = (float)A1[(size_t)(ci0 + cil) * HW + p0 + pix];
        if (scaleA) x *= scaleA[ci0 + cil];
        sA[((cil >> 3) * 32 + pix) * 8 + (cil & 7)] = f2b(x);
      }
    } else {
      const bf16* src; int cb; bool scl;
      if (!NCHW1 && ci0 < Ci1) {
        src = (const bf16*)(const void*)A1; cb = ci0; scl = false;
      } else {
        src = A2; cb = ci0 - Ci1; scl = true;
      }
      ushort4 raw = *(const ushort4*)&src[(size_t)(p0 + pix2) * 256 + cb + sub8 * 4];
      if (scl) {
        raw.x = f2us(us2f(raw.x) * scaleB);
        raw.y = f2us(us2f(raw.y) * scaleB);
        raw.z = f2us(us2f(raw.z) * scaleB);
        raw.w = f2us(us2f(raw.w) * scaleB);
      }
      *(ushort4*)&sA[((sub8 >> 1) * 32 + pix2) * 8 + (sub8 & 1) * 4] = raw;
    }
    __syncthreads();
    bf16x8 a = *(const bf16x8*)&sA[(q * 32 + pg * 16 + n) * 8];
    const bf16* bp = BP + ((size_t)(kc * 4 + q) * 256 + blockIdx.y * 128 + cg * 64) * 8;
#pragma unroll
    for (int nt = 0; nt < 4; ++nt) {
      bf16x8 b = *(const bf16x8*)&bp[(nt * 16 + n) * 8];
      acc[nt] = __builtin_amdgcn_mfma_f32_16x16x32_bf16(a, b, acc[nt], 0, 0, 0);
    }
    __syncthreads();
  }

  int pbase = p0 + pg * 16 + q * 4;
#pragma unroll
  for (int nt = 0; nt < 4; ++nt) {
    int o = blockIdx.y * 128 + cg * 64 + nt * 16 + n;
    float bv = bias ? bias[o] : 0.f;
#pragma unroll
    for (int r = 0; r < 4; ++r) {
      float v = acc[nt][r] + bv;
      if (out1) out1[(size_t)o * HW + pbase + r] = v;
      if (out2) out2[(size_t)(pbase + r) * ns2 + o] = f2b(v);
    }
  }
}

// ------------- 3x3 conv pad=1, MFMA implicit GEMM, NHWC(256) input -------
// Block: 32-px row segment x 128 o (grid (HW/32, 2)).
__global__ __launch_bounds__(256) void conv3x3_mfma_kernel(
    const bf16* __restrict__ in, const bf16* __restrict__ BP,
    const float* __restrict__ bias,
    int H, int W, int Co,
    float* __restrict__ out1, bf16* __restrict__ out2, int ns2) {
  __shared__ __align__(16) bf16 sA[9216];   // [9 tap][4 q][32 px][8]
  int HW = H * W;
  int segs = W >> 5;
  int y = blockIdx.x / segs;
  int x0 = (blockIdx.x - y * segs) << 5;
  int tid = threadIdx.x;
  int pix2 = tid >> 3, sub8 = tid & 7;
  int lane = tid & 63, wave = tid >> 6;
  int pg = wave & 1, cg = wave >> 1;
  int q = lane >> 4, n = lane & 15;

  floatx4 acc[4];
#pragma unroll
  for (int nt = 0; nt < 4; ++nt) acc[nt] = (floatx4)0.f;

  int xx = x0 + pix2;
  for (int kc = 0; kc < 8; ++kc) {
    int ci0 = kc << 5;
#pragma unroll
    for (int tap = 0; tap < 9; ++tap) {
      int dy = tap / 3 - 1, dx = tap % 3 - 1;
      int yy = y + dy, xg = xx + dx;
      ushort4 v = {0, 0, 0, 0};
      if ((unsigned)yy < (unsigned)H && (unsigned)xg < (unsigned)W)
        v = *(const ushort4*)&in[(size_t)(yy * W + xg) * 256 + ci0 + sub8 * 4];
      *(ushort4*)&sA[((tap * 4 + (sub8 >> 1)) * 32 + pix2) * 8 + (sub8 & 1) * 4] = v;
    }
    __syncthreads();
    const bf16* bpc = BP + (size_t)kc * 73728;  // kc*9*4*256*8
#pragma unroll
    for (int tap = 0; tap < 9; ++tap) {
      bf16x8 a = *(const bf16x8*)&sA[((tap * 4 + q) * 32 + pg * 16 + n) * 8];
      const bf16* bp =
          bpc + ((size_t)(tap * 4 + q) * 256 + blockIdx.y * 128 + cg * 64) * 8;
#pragma unroll
      for (int nt = 0; nt < 4; ++nt) {
        bf16x8 b = *(const bf16x8*)&bp[(nt * 16 + n) * 8];
        acc[nt] = __builtin_amdgcn_mfma_f32_16x16x32_bf16(a, b, acc[nt], 0, 0, 0);
      }
    }
    __syncthreads();
  }

  int pbase = y * W + x0 + pg * 16 + q * 4;
#pragma unroll
  for (int nt = 0; nt < 4; ++nt) {
    int o = blockIdx.y * 128 + cg * 64 + nt * 16 + n;
    if (o < Co) {
      float bv = bias ? bias[o] : 0.f;
#pragma unroll
      for (int r = 0; r < 4; ++r) {
        float v = acc[nt][r] + bv;
        if (out1) out1[(size_t)o * HW + pbase + r] = v;
        if (out2) out2[(size_t)(pbase + r) * ns2 + o] = f2b(v);
      }
    }
  }
}

// ---- mdcn v2: 8-px tile, NHWC gather + MFMA dot, + relu + bias + ARM ----
// UPn: NHWC(256); OM: NHWC(216); BP: packw1(dcn_w flat [256][2304]);
// ARM/F: NHWC(256).  grid = HW/8 blocks.
__global__ __launch_bounds__(256) void mdcn_mfma_kernel(
    const bf16* __restrict__ UPn, const bf16* __restrict__ OM,
    const bf16* __restrict__ BP, const float* __restrict__ dcn_b,
    const bf16* __restrict__ ARM, bf16* __restrict__ F,
    int H, int W, int wshift) {
  // [288 kq][8 px][8] + 8-elem pad per block (72 bf16/block) + tail pad
  __shared__ __align__(16) bf16 sval[288 * 72 + 72];
  int pb = blockIdx.x * 8;
  int tid = threadIdx.x;
  int l = tid & 31;       // channel-in-group lane
  int hw = tid >> 5;      // half-wave 0..7
  for (int it = 0; it < 72; ++it) {
    int task = it * 8 + hw;            // 0..575 = gk*8 + px
    int px = task & 7;
    int gk = task >> 3;                // 0..71
    int g = gk / 9, kt = gk - g * 9;
    int ky = kt / 3, kx = kt - ky * 3;
    int p = pb + px;
    int y = p >> wshift, x = p & (W - 1);
    const bf16* omp = OM + (size_t)p * 216;
    float dy = b2f(omp[g * 18 + kt]);
    float dx = b2f(omp[g * 18 + 9 + kt]);
    float mm = 1.f / (1.f + expf(-b2f(omp[144 + g * 9 + kt])));
    float fpy = (float)(y - 1 + ky) + dy;
    float fpx = (float)(x - 1 + kx) + dx;
    fpy = fminf(fmaxf(fpy, -1.0e4f), 1.0e4f);
    fpx = fminf(fmaxf(fpx, -1.0e4f), 1.0e4f);
    float fy0 = floorf(fpy), fx0 = floorf(fpx);
    float wy1 = fpy - fy0, wx1 = fpx - fx0;
    int iy0 = (int)fy0, ix0 = (int)fx0;
    bool vy0 = ((unsigned)iy0 < (unsigned)H);
    bool vy1 = ((unsigned)(iy0 + 1) < (unsigned)H);
    bool vx0 = ((unsigned)ix0 < (unsigned)W);
    bool vx1 = ((unsigned)(ix0 + 1) < (unsigned)W);
    const bf16* up = UPn + (size_t)(iy0 * W + ix0) * 256 + g * 32 + l;
    float v00 = (vy0 && vx0) ? b2f(up[0]) : 0.f;
    float v01 = (vy0 && vx1) ? b2f(up[256]) : 0.f;
    float v10 = (vy1 && vx0) ? b2f(up[(size_t)W * 256]) : 0.f;
    float v11 = (vy1 && vx1) ? b2f(up[(size_t)W * 256 + 256]) : 0.f;
    float sv = mm * ((1.f - wy1) * ((1.f - wx1) * v00 + wx1 * v01)
                   + wy1 * ((1.f - wx1) * v10 + wx1 * v11));
    int K = (g * 32 + l) * 9 + kt;     // matches packw1 k-index (ci*9+tap)
    sval[(K >> 3) * 72 + px * 8 + (K & 7)] = f2b(sv);
  }
  __syncthreads();

  int lane = tid & 63, wave = tid >> 6;
  int q = lane >> 4, n = lane & 15;
  floatx4 acc[4];
#pragma unroll
  for (int nt = 0; nt < 4; ++nt) acc[nt] = (floatx4)0.f;
  for (int kc = 0; kc < 72; ++kc) {
    // rows n>=8 read pad/garbage; their D-rows are never stored (q<2 guard)
    bf16x8 a = *(const bf16x8*)&sval[(kc * 4 + q) * 72 + n * 8];
    const bf16* bp = BP + ((size_t)(kc * 4 + q) * 256 + wave * 64) * 8;
#pragma unroll
    for (int nt = 0; nt < 4; ++nt) {
      bf16x8 b = *(const bf16x8*)&bp[(nt * 16 + n) * 8];
      acc[nt] = __builtin_amdgcn_mfma_f32_16x16x32_bf16(a, b, acc[nt], 0, 0, 0);
    }
  }
  if (q < 2) {
    int pbase = pb + q * 4;
#pragma unroll
    for (int nt = 0; nt < 4; ++nt) {
      int o = wave * 64 + nt * 16 + n;
      float bv = dcn_b[o];
#pragma unroll
      for (int r = 0; r < 4; ++r) {
        int p = pbase + r;
        float v = fmaxf(acc[nt][r] + bv, 0.f) + b2f(ARM[(size_t)p * 256 + o]);
        F[(size_t)p * 256 + o] = f2b(v);
      }
    }
  }
}

extern "C" void kernel_launch(void* const* d_in, const int* in_sizes, int n_in,
                              void* d_out, int out_size, void* d_ws, size_t ws_size,
                              hipStream_t stream) {
  // Inputs fp32, outputs fp32 (established rounds 3-5). Interior: bf16 NHWC.
  const float* c2 = (const float*)d_in[0];
  const float* c3 = (const float*)d_in[1];
  const float* c4 = (const float*)d_in[2];
  const float* c5 = (const float*)d_in[3];
  const float* lat_w = (const float*)d_in[31];
  const float* lat_b = (const float*)d_in[32];
  float* out = (float*)d_out;
  (void)ws_size; (void)in_sizes; (void)n_in; (void)out_size;

  const size_t p2_off = 0;
  const size_t p3_off = 4194304;
  const size_t p4_off = p3_off + 1048576;
  const size_t p5_off = p4_off + 262144;

  // ---- ws layout (~25.3MB; ws_size >= 28MB proven round 3) ----
  char* ws = (char*)d_ws;
  bf16* UPn = (bf16*)(ws);                    // 8MB NHWC
  bf16* ARM = (bf16*)(ws + 8388608);          // 8MB NHWC
  bf16* FB  = (bf16*)(ws + 16777216);         // 8MB NHWC (off_feat & F alias)
  bf16* P5N = (bf16*)(ws + 25165824);         // 128KB NHWC p5 copy
  bf16* BPB = (bf16*)(ws + 25296896);         // 1.125MB packed-B scratch
  float* GAP = (float*)(ws + 26476544);
  float* SC  = (float*)(ws + 26484736);
  // OM (NHWC stride 216, 6.75MB max) borrows the p2 output region (16.8MB);
  // p2 is written only by the final conv, after mdcn consumed OM.
  bf16* OM = (bf16*)(out + p2_off);

  // ---- p5 = conv1x1(c5, lat_w, lat_b): fp32 NCHW out + bf16 NHWC copy ----
  packw1_kernel<<<2048, 256, 0, stream>>>(lat_w, BPB, 2048);
  conv1x1_mfma_kernel<true, float><<<dim3(8, 2), 256, 0, stream>>>(
      c5, nullptr, nullptr, 0.f, 2048, 0, 256, BPB, lat_b,
      out + p5_off, P5N, 256);

  struct Lv {
    const float* featl; int Ci; int H; int W; int wshift;
    float* pdst; int wbase;
  };
  Lv levels[3] = {
      {c4, 1024, 32, 32, 5, out + p4_off, 4},
      {c3, 512, 64, 64, 6, out + p3_off, 13},
      {c2, 256, 128, 128, 7, out + p2_off, 22},
  };

  for (int li = 0; li < 3; ++li) {
    const Lv& L = levels[li];
    const float* att_w = (const float*)d_in[L.wbase + 0];
    const float* fsm_w = (const float*)d_in[L.wbase + 1];
    const float* off_w = (const float*)d_in[L.wbase + 2];
    const float* om_w  = (const float*)d_in[L.wbase + 3];
    const float* om_b  = (const float*)d_in[L.wbase + 4];
    const float* dcn_w = (const float*)d_in[L.wbase + 5];
    const float* dcn_b = (const float*)d_in[L.wbase + 6];
    const float* out_w = (const float*)d_in[L.wbase + 7];
    const float* out_b = (const float*)d_in[L.wbase + 8];
    int HW = L.H * L.W;

    // 1) feat_up = bilinear 2x (NHWC -> NHWC): src = P5N or previous F(FB)
    upsample2x_nhwc_kernel<<<HW, 256, 0, stream>>>(
        (li == 0) ? P5N : FB, UPn, L.H / 2, L.W / 2);
    // 2) FSM: gap -> atten -> scaled 1x1 GEMM -> ARM (NHWC)
    gap_kernel<<<L.Ci, 256, 0, stream>>>(L.featl, GAP, HW, 1.f / (float)HW);
    atten_kernel<<<L.Ci / 256, 256, 0, stream>>>(att_w, GAP, SC, L.Ci);
    packw1_kernel<<<L.Ci, 256, 0, stream>>>(fsm_w, BPB, L.Ci);
    conv1x1_mfma_kernel<true, float><<<dim3(HW / 32, 2), 256, 0, stream>>>(
        L.featl, SC, nullptr, 0.f, L.Ci, 0, HW, BPB, nullptr,
        nullptr, ARM, 256);
    // 3) off_feat = conv1x1(concat(ARM, 2*UPn)) -> FB (NHWC)
    packw1_kernel<<<512, 256, 0, stream>>>(off_w, BPB, 512);
    conv1x1_mfma_kernel<false, bf16><<<dim3(HW / 32, 2), 256, 0, stream>>>(
        ARM, nullptr, UPn, 2.f, 256, 256, HW, BPB, nullptr,
        nullptr, FB, 256);
    // 4) om = conv3x3(FB) + om_b -> OM (NHWC stride 216, in p2 region)
    packw3_kernel<<<2304, 256, 0, stream>>>(om_w, BPB, 256, 216);
    conv3x3_mfma_kernel<<<dim3(HW / 32, 2), 256, 0, stream>>>(
        FB, BPB, om_b, L.H, L.W, 216, nullptr, OM, 216);
    // 5) F = relu(mdcn(UPn, OM) + dcn_b) + ARM -> FB (NHWC)
    packw1_kernel<<<2304, 256, 0, stream>>>(dcn_w, BPB, 2304);
    mdcn_mfma_kernel<<<HW / 8, 256, 0, stream>>>(
        UPn, OM, BPB, dcn_b, ARM, FB, L.H, L.W, L.wshift);
    // 6) p = conv3x3(F) + out_b -> fp32 NCHW output
    packw3_kernel<<<2304, 256, 0, stream>>>(out_w, BPB, 256, 256);
    conv3x3_mfma_kernel<<<dim3(HW / 32, 2), 256, 0, stream>>>(
        FB, BPB, out_b, L.H, L.W, 256, L.pdst, nullptr, 256);
  }
}